// Round 1
// baseline (201.230 us; speedup 1.0000x reference)
//
#include <hip/hip_runtime.h>
#include <cstdint>

#define ALPHA 0.2f
#define NEG_INF -9000000000000000.0f
// Fixed problem shape: B=8, N=1024, Din=Dout=256, M = B*N = 8192

// ---------------- Kernel 1: Wh[m][f] = sum_d h[m][d] * W[f][d] ----------------
// 64x64 output tile per block, 256 threads (16x16), 4x4 per thread, BK=32.
__global__ __launch_bounds__(256) void k_gemm1(
    const float* __restrict__ h, const float* __restrict__ W, float* __restrict__ Wh)
{
  __shared__ float As[32][68]; // [k][m], row stride 68 floats = 272 B (16B-aligned)
  __shared__ float Bs[32][68]; // [k][f]
  const int m0 = blockIdx.x * 64;
  const int f0 = blockIdx.y * 64;
  const int tid = threadIdx.x;
  const int tm = tid >> 4, tf = tid & 15;
  float acc[4][4] = {};
  for (int k0 = 0; k0 < 256; k0 += 32) {
#pragma unroll
    for (int l = 0; l < 2; l++) {
      int idx = tid + l * 256;      // 0..511
      int r = idx >> 3;             // 0..63
      int c = (idx & 7) << 2;       // 0,4,...,28
      float4 va = *(const float4*)(h + (size_t)(m0 + r) * 256 + k0 + c);
      As[c + 0][r] = va.x; As[c + 1][r] = va.y; As[c + 2][r] = va.z; As[c + 3][r] = va.w;
      float4 vb = *(const float4*)(W + (size_t)(f0 + r) * 256 + k0 + c);
      Bs[c + 0][r] = vb.x; Bs[c + 1][r] = vb.y; Bs[c + 2][r] = vb.z; Bs[c + 3][r] = vb.w;
    }
    __syncthreads();
#pragma unroll
    for (int k = 0; k < 32; k++) {
      float a[4], bb[4];
      *(float4*)a  = *(const float4*)&As[k][tm * 4];
      *(float4*)bb = *(const float4*)&Bs[k][tf * 4];
#pragma unroll
      for (int i = 0; i < 4; i++)
#pragma unroll
        for (int j = 0; j < 4; j++)
          acc[i][j] = fmaf(a[i], bb[j], acc[i][j]);
    }
    __syncthreads();
  }
#pragma unroll
  for (int i = 0; i < 4; i++) {
    float4 v = make_float4(acc[i][0], acc[i][1], acc[i][2], acc[i][3]);
    *(float4*)(Wh + (size_t)(m0 + tm * 4 + i) * 256 + f0 + tf * 4) = v;
  }
}

// ---------------- Kernel 2: src[m] = Wh[m]·a1, dst[m] = Wh[m]·a2 ----------------
__global__ __launch_bounds__(256) void k_srcdst(
    const float* __restrict__ Wh, const float* __restrict__ a,
    float* __restrict__ src, float* __restrict__ dst)
{
  const int m = blockIdx.x;
  const int t = threadIdx.x;
  float wh = Wh[(size_t)m * 256 + t];
  float s1 = wh * a[t];
  float s2 = wh * a[256 + t];
#pragma unroll
  for (int off = 32; off; off >>= 1) {
    s1 += __shfl_down(s1, off, 64);
    s2 += __shfl_down(s2, off, 64);
  }
  __shared__ float r1[4], r2[4];
  int w = t >> 6;
  if ((t & 63) == 0) { r1[w] = s1; r2[w] = s2; }
  __syncthreads();
  if (t == 0) {
    src[m] = r1[0] + r1[1] + r1[2] + r1[3];
    dst[m] = r2[0] + r2[1] + r2[2] + r2[3];
  }
}

// ---------------- Kernel 3: fused mask + softmax + aggregate ----------------
// One block = (batch b, 16 consecutive i rows). 256 threads.
__global__ __launch_bounds__(256) void k_attn(
    const float* __restrict__ Wh, const int* __restrict__ adj,
    const float* __restrict__ src, const float* __restrict__ dst,
    float* __restrict__ out)
{
  const int b  = blockIdx.x & 7;          // batch -> XCD affinity (round-robin dispatch)
  const int i0 = (blockIdx.x >> 3) << 4;  // * 16
  const int t  = threadIdx.x;
  const int wv = t >> 6, lane = t & 63;

  __shared__ float dstS[1024];
  __shared__ float srcS[16];
  __shared__ unsigned long long maskS[16][16]; // [i][j/64] adjacency bits
  __shared__ float partM[16][4], partL[16][4];
  __shared__ float mS[16], lS[16];             // row max, 1/rowsum
  __shared__ float pS[256][20];                // [j-in-tile][i], padded stride 20

  *(float4*)&dstS[t * 4] = *(const float4*)(dst + b * 1024 + t * 4);
  if (t < 16) srcS[t] = src[b * 1024 + i0 + t];
  __syncthreads();

  // ---- Pass A: per-row max & sum of exp, pack adj bits ----
  for (int i = 0; i < 16; i++) {
    float si = srcS[i];
    const int* arow = adj + ((size_t)b * 1024 + i0 + i) * 1024;
    float e4[4];
#pragma unroll
    for (int k = 0; k < 4; k++) {
      int j = k * 256 + t;
      int av = arow[j];
      float v = si + dstS[j];
      float vl = v > 0.f ? v : ALPHA * v;
      e4[k] = (av > 0) ? vl : NEG_INF;
      unsigned long long bm = __ballot(av > 0);
      if (lane == 0) maskS[i][k * 4 + wv] = bm;
    }
    float mt = fmaxf(fmaxf(e4[0], e4[1]), fmaxf(e4[2], e4[3]));
    float lt = __expf(e4[0] - mt) + __expf(e4[1] - mt) +
               __expf(e4[2] - mt) + __expf(e4[3] - mt);
#pragma unroll
    for (int off = 32; off; off >>= 1) {
      float m2 = __shfl_down(mt, off, 64);
      float l2 = __shfl_down(lt, off, 64);
      float nm = fmaxf(mt, m2);
      lt = lt * __expf(mt - nm) + l2 * __expf(m2 - nm);
      mt = nm;
    }
    if (lane == 0) { partM[i][wv] = mt; partL[i][wv] = lt; }
  }
  __syncthreads();
  if (t < 16) {
    float M = fmaxf(fmaxf(partM[t][0], partM[t][1]), fmaxf(partM[t][2], partM[t][3]));
    float L = partL[t][0] * __expf(partM[t][0] - M) + partL[t][1] * __expf(partM[t][1] - M) +
              partL[t][2] * __expf(partM[t][2] - M) + partL[t][3] * __expf(partM[t][3] - M);
    mS[t] = M;
    lS[t] = 1.0f / L;   // L >= 1 always (max term contributes exp(0))
  }
  __syncthreads();

  // ---- Pass B: p = exp(e - m), h' = (p @ Wh) / L ----
  float acc[16] = {};
  const float* whcol = Wh + (size_t)b * 1024 * 256 + t;  // thread owns feature f = t
  for (int jt = 0; jt < 4; jt++) {
    int j = jt * 256 + t;
    float dj = dstS[j];
    float pr[16];
#pragma unroll
    for (int i = 0; i < 16; i++) {
      unsigned long long w64 = maskS[i][jt * 4 + wv];
      int bit = (int)((w64 >> lane) & 1ull);
      float v = srcS[i] + dj;
      float vl = v > 0.f ? v : ALPHA * v;
      float e = bit ? vl : NEG_INF;      // fully-masked row: e-m = 0 -> uniform, matches ref
      pr[i] = __expf(e - mS[i]);
    }
    __syncthreads();   // protect previous tile's pS reads
#pragma unroll
    for (int q = 0; q < 4; q++)
      *(float4*)&pS[t][q * 4] = make_float4(pr[q * 4], pr[q * 4 + 1], pr[q * 4 + 2], pr[q * 4 + 3]);
    __syncthreads();

    const float* whj = whcol + (size_t)jt * 256 * 256;
#pragma unroll 8
    for (int j2 = 0; j2 < 256; j2++) {
      float wh = whj[(size_t)j2 * 256];
      float4 p0 = *(const float4*)&pS[j2][0];
      float4 p1 = *(const float4*)&pS[j2][4];
      float4 p2 = *(const float4*)&pS[j2][8];
      float4 p3 = *(const float4*)&pS[j2][12];
      acc[0]  = fmaf(p0.x, wh, acc[0]);  acc[1]  = fmaf(p0.y, wh, acc[1]);
      acc[2]  = fmaf(p0.z, wh, acc[2]);  acc[3]  = fmaf(p0.w, wh, acc[3]);
      acc[4]  = fmaf(p1.x, wh, acc[4]);  acc[5]  = fmaf(p1.y, wh, acc[5]);
      acc[6]  = fmaf(p1.z, wh, acc[6]);  acc[7]  = fmaf(p1.w, wh, acc[7]);
      acc[8]  = fmaf(p2.x, wh, acc[8]);  acc[9]  = fmaf(p2.y, wh, acc[9]);
      acc[10] = fmaf(p2.z, wh, acc[10]); acc[11] = fmaf(p2.w, wh, acc[11]);
      acc[12] = fmaf(p3.x, wh, acc[12]); acc[13] = fmaf(p3.y, wh, acc[13]);
      acc[14] = fmaf(p3.z, wh, acc[14]); acc[15] = fmaf(p3.w, wh, acc[15]);
    }
  }

#pragma unroll
  for (int i = 0; i < 16; i++)
    out[((size_t)b * 1024 + i0 + i) * 256 + t] = acc[i] * lS[i];
}

// ---------------- Launch ----------------
extern "C" void kernel_launch(void* const* d_in, const int* in_sizes, int n_in,
                              void* d_out, int out_size, void* d_ws, size_t ws_size,
                              hipStream_t stream) {
  const float* h   = (const float*)d_in[0];   // (8,1024,256) f32
  const int*   adj = (const int*)d_in[1];     // (8,1024,1024) i32
  const float* W   = (const float*)d_in[2];   // (256,256) f32
  const float* a   = (const float*)d_in[3];   // (512,1) f32
  float* out = (float*)d_out;                 // (8,1024,256) f32

  float* Wh   = (float*)d_ws;                               // 8 MB
  float* srcv = (float*)((char*)d_ws + (size_t)8 * 1024 * 1024);
  float* dstv = srcv + 8192;

  k_gemm1<<<dim3(128, 4), 256, 0, stream>>>(h, W, Wh);
  k_srcdst<<<8192, 256, 0, stream>>>(Wh, a, srcv, dstv);
  k_attn<<<512, 256, 0, stream>>>(Wh, adj, srcv, dstv, out);
}

// Round 2
// 136.448 us; speedup vs baseline: 1.4748x; 1.4748x over previous
//
#include <hip/hip_runtime.h>
#include <hip/hip_bf16.h>
#include <cstdint>

#define ALPHA 0.2f
#define NEG_INF -9000000000000000.0f
// B=8, N=1024, Din=Dout=256, M = 8192
// ws layout:
//   WhT bf16 [8][256][1024]   @ 0        (4 MiB)   B^T layout for MFMA B-frags
//   src  f32 [8192]           @ 4 MiB
//   dst  f32 [8192]           @ 4 MiB + 32 KiB
//   m    f32 [8192]           @ 4 MiB + 64 KiB
//   linv f32 [8192]           @ 4 MiB + 96 KiB
//   mask u64 [8192][16]       @ 4 MiB + 128 KiB    (1 MiB)  total 5.125 MiB

typedef __bf16 bf16_t;
typedef __bf16 bf16x8 __attribute__((ext_vector_type(8)));
typedef float f32x16 __attribute__((ext_vector_type(16)));

__global__ __launch_bounds__(256) void k_zero(float* __restrict__ p) {
  *(float4*)(p + (size_t)blockIdx.x * 1024 + threadIdx.x * 4) = make_float4(0.f, 0.f, 0.f, 0.f);
}

// ---------------- Kernel 1: fp32 GEMM; epilogue -> WhT bf16 + src/dst atomics ----------------
__global__ __launch_bounds__(256) void k_gemm1(
    const float* __restrict__ h, const float* __restrict__ W, const float* __restrict__ a,
    bf16_t* __restrict__ WhT, float* __restrict__ src, float* __restrict__ dst)
{
  __shared__ float smem[64 * 68];          // k-loop: As[32][68] + Bs[32][68]; epilogue: [64 m][68]
  float* As = smem;
  float* Bs = smem + 32 * 68;
  const int m0 = blockIdx.x * 64;
  const int f0 = blockIdx.y * 64;
  const int tid = threadIdx.x;
  const int tm = tid >> 4, tf = tid & 15;
  float acc[4][4] = {};
  for (int k0 = 0; k0 < 256; k0 += 32) {
#pragma unroll
    for (int l = 0; l < 2; l++) {
      int idx = tid + l * 256;
      int r = idx >> 3;
      int c = (idx & 7) << 2;
      float4 va = *(const float4*)(h + (size_t)(m0 + r) * 256 + k0 + c);
      As[(c + 0) * 68 + r] = va.x; As[(c + 1) * 68 + r] = va.y;
      As[(c + 2) * 68 + r] = va.z; As[(c + 3) * 68 + r] = va.w;
      float4 vb = *(const float4*)(W + (size_t)(f0 + r) * 256 + k0 + c);
      Bs[(c + 0) * 68 + r] = vb.x; Bs[(c + 1) * 68 + r] = vb.y;
      Bs[(c + 2) * 68 + r] = vb.z; Bs[(c + 3) * 68 + r] = vb.w;
    }
    __syncthreads();
#pragma unroll
    for (int k = 0; k < 32; k++) {
      float av[4], bv[4];
      *(float4*)av = *(const float4*)&As[k * 68 + tm * 4];
      *(float4*)bv = *(const float4*)&Bs[k * 68 + tf * 4];
#pragma unroll
      for (int i = 0; i < 4; i++)
#pragma unroll
        for (int j = 0; j < 4; j++)
          acc[i][j] = fmaf(av[i], bv[j], acc[i][j]);
    }
    __syncthreads();
  }

  // ---- epilogue A: stage tile [m_local][f_local] into smem for transpose ----
#pragma unroll
  for (int i = 0; i < 4; i++)
    *(float4*)&smem[(tm * 4 + i) * 68 + tf * 4] =
        make_float4(acc[i][0], acc[i][1], acc[i][2], acc[i][3]);
  __syncthreads();
  // ---- epilogue B: WhT[b][f][j] bf16 write, coalesced-ish rows ----
  {
    const int fl = tid >> 2;              // 0..63
    const int jq = (tid & 3) * 16;        // 0,16,32,48
    const int b  = m0 >> 10;
    const int j0 = m0 & 1023;
    bf16x8 v0, v1;
#pragma unroll
    for (int k = 0; k < 8; k++) {
      v0[k] = (bf16_t)smem[(jq + k) * 68 + fl];
      v1[k] = (bf16_t)smem[(jq + 8 + k) * 68 + fl];
    }
    bf16_t* dp = WhT + (((size_t)(b * 256 + f0 + fl)) << 10) + j0 + jq;
    *(bf16x8*)dp = v0;
    *(bf16x8*)(dp + 8) = v1;
  }
  // ---- epilogue C: src/dst partials (from fp32 accs, pre-rounding) ----
  {
    float a1v[4], a2v[4];
#pragma unroll
    for (int j = 0; j < 4; j++) {
      a1v[j] = a[f0 + tf * 4 + j];
      a2v[j] = a[256 + f0 + tf * 4 + j];
    }
#pragma unroll
    for (int i = 0; i < 4; i++) {
      float s1 = 0.f, s2 = 0.f;
#pragma unroll
      for (int j = 0; j < 4; j++) {
        s1 = fmaf(acc[i][j], a1v[j], s1);
        s2 = fmaf(acc[i][j], a2v[j], s2);
      }
#pragma unroll
      for (int off = 8; off; off >>= 1) {   // reduce over tf (16-lane groups)
        s1 += __shfl_down(s1, off, 16);
        s2 += __shfl_down(s2, off, 16);
      }
      if (tf == 0) {
        atomicAdd(&src[m0 + tm * 4 + i], s1);
        atomicAdd(&dst[m0 + tm * 4 + i], s2);
      }
    }
  }
}

// ---------------- Kernel 2: row stats (max, 1/sumexp) + adjacency bitmask ----------------
__global__ __launch_bounds__(256) void k_stats(
    const int* __restrict__ adj, const float* __restrict__ src, const float* __restrict__ dst,
    float* __restrict__ m_ws, float* __restrict__ linv_ws,
    unsigned long long* __restrict__ mask_ws)
{
  const int b  = blockIdx.x & 7;
  const int i0 = (blockIdx.x >> 3) << 3;   // 8 rows per block
  const int t  = threadIdx.x;
  const int wv = t >> 6, lane = t & 63;
  __shared__ float dstS[1024];
  __shared__ float srcS[8];
  __shared__ float partM[8][4], partL[8][4];
  *(float4*)&dstS[t * 4] = *(const float4*)(dst + (b << 10) + t * 4);
  if (t < 8) srcS[t] = src[(b << 10) + i0 + t];
  __syncthreads();

  for (int i = 0; i < 8; i++) {
    float si = srcS[i];
    const int* arow = adj + (((size_t)(b << 10) + i0 + i) << 10);
    float e4[4];
#pragma unroll
    for (int k = 0; k < 4; k++) {
      int j = k * 256 + t;
      int av = arow[j];
      float v = si + dstS[j];
      float vl = fmaxf(v, ALPHA * v);     // leaky relu
      e4[k] = (av > 0) ? vl : NEG_INF;
      unsigned long long bm = __ballot(av > 0);
      if (lane == 0) mask_ws[((size_t)(b << 10) + i0 + i) * 16 + k * 4 + wv] = bm;
    }
    float mt = fmaxf(fmaxf(e4[0], e4[1]), fmaxf(e4[2], e4[3]));
    float lt = __expf(e4[0] - mt) + __expf(e4[1] - mt) +
               __expf(e4[2] - mt) + __expf(e4[3] - mt);
#pragma unroll
    for (int off = 32; off; off >>= 1) {
      float m2 = __shfl_down(mt, off, 64);
      float l2 = __shfl_down(lt, off, 64);
      float nm = fmaxf(mt, m2);
      lt = lt * __expf(mt - nm) + l2 * __expf(m2 - nm);
      mt = nm;
    }
    if (lane == 0) { partM[i][wv] = mt; partL[i][wv] = lt; }
  }
  __syncthreads();
  if (t < 8) {
    float M = fmaxf(fmaxf(partM[t][0], partM[t][1]), fmaxf(partM[t][2], partM[t][3]));
    float L = partL[t][0] * __expf(partM[t][0] - M) + partL[t][1] * __expf(partM[t][1] - M) +
              partL[t][2] * __expf(partM[t][2] - M) + partL[t][3] * __expf(partM[t][3] - M);
    m_ws[(b << 10) + i0 + t] = M;
    linv_ws[(b << 10) + i0 + t] = 1.0f / L;
  }
}

// ---------------- Kernel 3: P (bf16) + MFMA aggregation ----------------
// grid 512 = b(8) x fhalf(2) x itile(32 rows, 32 tiles). 256 threads = 4 waves,
// wave w owns f-tile [fh*128 + w*32, +32).
__global__ __launch_bounds__(256) void k_attn(
    const bf16_t* __restrict__ WhT, const float* __restrict__ src, const float* __restrict__ dst,
    const float* __restrict__ m_ws, const float* __restrict__ linv_ws,
    const unsigned long long* __restrict__ mask_ws, float* __restrict__ out)
{
  const int b  = blockIdx.x & 7;
  const int fh = (blockIdx.x >> 3) & 1;
  const int i0 = (blockIdx.x >> 4) << 5;
  const int t  = threadIdx.x;
  const int w  = t >> 6;
  const int lane = t & 63;
  const int mrow = lane & 31, half = lane >> 5;

  __shared__ float dstS[1024];
  __shared__ float srcS[32], mS[32], lInvS[32];
  __shared__ unsigned long long maskS[32 * 16];
  __shared__ bf16_t P[32 * 264];     // [i][j-chunk 256], pad 264 -> stride 132 dw (conflict-free b128)
  __shared__ bf16_t WhS[128 * 72];   // [f][j-sub 64], pad 72 -> stride 36 dw (conflict-free b128)

  *(float4*)&dstS[t * 4] = *(const float4*)(dst + (b << 10) + t * 4);
  if (t < 32) {
    srcS[t]  = src[(b << 10) + i0 + t];
    mS[t]    = m_ws[(b << 10) + i0 + t];
    lInvS[t] = linv_ws[(b << 10) + i0 + t];
  }
  {
    const size_t mb = ((size_t)(b << 10) + i0) * 16;
    maskS[t]       = mask_ws[mb + t];
    maskS[t + 256] = mask_ws[mb + t + 256];
  }
  __syncthreads();

  f32x16 acc;
#pragma unroll
  for (int r = 0; r < 16; r++) acc[r] = 0.f;

  const size_t whbase = ((size_t)(b * 256 + fh * 128)) << 10;

  for (int c = 0; c < 4; c++) {
    // ---- P for this 256-j chunk: thread t owns j = c*256+t, all 32 i ----
    {
      float dj = dstS[c * 256 + t];
      int mi = c * 4 + (t >> 6);
      int sh = t & 63;
#pragma unroll 8
      for (int i = 0; i < 32; i++) {
        unsigned long long w64 = maskS[i * 16 + mi];
        float v = srcS[i] + dj;
        float vl = fmaxf(v, ALPHA * v);
        float e = ((w64 >> sh) & 1ull) ? vl : NEG_INF;
        P[i * 264 + t] = (bf16_t)__expf(e - mS[i]);
      }
    }
    __syncthreads();

    for (int s = 0; s < 4; s++) {
      // ---- stage WhT[f=fh*128..+128][64 j] -> WhS (padded rows) ----
      const size_t gbase = whbase + c * 256 + s * 64;
#pragma unroll
      for (int it = 0; it < 4; it++) {
        int idx = it * 256 + t;
        int f  = idx >> 3;
        int jb = (idx & 7) << 3;
        uint4 v = *(const uint4*)(WhT + gbase + ((size_t)f << 10) + jb);
        *(uint4*)&WhS[f * 72 + jb] = v;
      }
      __syncthreads();
#pragma unroll
      for (int ks = 0; ks < 4; ks++) {
        bf16x8 af = *(const bf16x8*)&P[mrow * 264 + s * 64 + ks * 16 + half * 8];
        bf16x8 bf = *(const bf16x8*)&WhS[(w * 32 + mrow) * 72 + ks * 16 + half * 8];
        acc = __builtin_amdgcn_mfma_f32_32x32x16_bf16(af, bf, acc, 0, 0, 0);
      }
      __syncthreads();
    }
  }

  // ---- epilogue: D col=lane&31, row=(reg&3)+8*(reg>>2)+4*(lane>>5) ----
  const int col = fh * 128 + w * 32 + mrow;
#pragma unroll
  for (int r = 0; r < 16; r++) {
    int row = (r & 3) + 8 * (r >> 2) + 4 * half;
    out[((size_t)(b << 10) + i0 + row) * 256 + col] = acc[r] * lInvS[row];
  }
}

// ---------------- Launch ----------------
extern "C" void kernel_launch(void* const* d_in, const int* in_sizes, int n_in,
                              void* d_out, int out_size, void* d_ws, size_t ws_size,
                              hipStream_t stream) {
  const float* h   = (const float*)d_in[0];
  const int*   adj = (const int*)d_in[1];
  const float* W   = (const float*)d_in[2];
  const float* a   = (const float*)d_in[3];
  float* out = (float*)d_out;

  char* wsb = (char*)d_ws;
  bf16_t* WhT = (bf16_t*)wsb;
  float* srcv = (float*)(wsb + (4u << 20));
  float* dstv = srcv + 8192;
  float* m_ws = srcv + 16384;
  float* linv = srcv + 24576;
  unsigned long long* mask_ws = (unsigned long long*)(wsb + (4u << 20) + 131072);

  k_zero<<<16, 256, 0, stream>>>(srcv);                       // src+dst contiguous 64 KiB
  k_gemm1<<<dim3(128, 4), 256, 0, stream>>>(h, W, a, WhT, srcv, dstv);
  k_stats<<<1024, 256, 0, stream>>>(adj, srcv, dstv, m_ws, linv, mask_ws);
  k_attn<<<512, 256, 0, stream>>>(WhT, srcv, dstv, m_ws, linv, mask_ws, out);
}

// Round 3
// 130.855 us; speedup vs baseline: 1.5378x; 1.0427x over previous
//
#include <hip/hip_runtime.h>
#include <hip/hip_bf16.h>
#include <cstdint>

#define ALPHA 0.2f
#define NEG_INF -9000000000000000.0f
// B=8, N=1024, Din=Dout=256, M = 8192
// ws layout:
//   WhT bf16 [8][256][1024]   @ 0            (4 MiB)  B^T layout for MFMA B-frags
//   src  f32 [8192]           @ 4 MiB
//   dst  f32 [8192]           @ 4 MiB + 32 KiB
//   m    f32 [8192]           @ 4 MiB + 64 KiB
//   linv f32 [8192]           @ 4 MiB + 96 KiB
//   mask u64 [8192][16]       @ 4 MiB + 128 KiB  (1 MiB)
//   u1/u2 f32 [512]           @ 5 MiB + 128 KiB  (2 KiB)

typedef __bf16 bf16_t;
typedef __bf16 bf16x8 __attribute__((ext_vector_type(8)));
typedef float f32x16 __attribute__((ext_vector_type(16)));

// ---------------- Kernel 0: u1 = W^T a1, u2 = W^T a2 (one block) ----------------
__global__ __launch_bounds__(256) void k_prep(
    const float* __restrict__ W, const float* __restrict__ a, float* __restrict__ u)
{
  const int d = threadIdx.x;
  float s1a = 0.f, s1b = 0.f, s2a = 0.f, s2b = 0.f;
#pragma unroll 4
  for (int f = 0; f < 256; f += 2) {
    float w0 = W[f * 256 + d];
    float w1 = W[(f + 1) * 256 + d];
    s1a = fmaf(w0, a[f], s1a);       s1b = fmaf(w1, a[f + 1], s1b);
    s2a = fmaf(w0, a[256 + f], s2a); s2b = fmaf(w1, a[256 + f + 1], s2b);
  }
  u[d] = s1a + s1b;
  u[256 + d] = s2a + s2b;
}

// ---------------- Kernel 1: WhT[b][f][j] = bf16( sum_d W[f][d] h[bj][d] ) via MFMA ----------------
// 512 blocks = b(8) x jt(16) x ft(4); 256 threads = 4 waves; block tile 64f x 64j;
// wave tile 32x32 (one 32x32x16 accumulator). BK=64, 4 stages.
__global__ __launch_bounds__(256) void k_gemm1(
    const float* __restrict__ h, const float* __restrict__ W, bf16_t* __restrict__ WhT)
{
  __shared__ bf16_t WS[64 * 72];   // [f_local][d_chunk], stride 72 (36 dw % 32 == 4 -> clean)
  __shared__ bf16_t HS[64 * 72];   // [j_local][d_chunk]
  const int bx = blockIdx.x;
  const int b  = bx & 7;
  const int jt = (bx >> 3) & 15;
  const int ft = bx >> 7;
  const int j0 = jt * 64, f0 = ft * 64;
  const int t = threadIdx.x;
  const int w = t >> 6, lane = t & 63;
  const int mrow = lane & 31, half = lane >> 5;
  const int fsub = (w & 1) * 32, jsub = (w >> 1) * 32;

  const int lr = t >> 2;          // 0..63 (row)
  const int lc = (t & 3) * 16;    // 0,16,32,48 (col group)
  const float* wp = W + ((size_t)(f0 + lr)) * 256 + lc;
  const float* hp = h + ((size_t)(b * 1024 + j0 + lr)) * 256 + lc;

  f32x16 acc;
#pragma unroll
  for (int r = 0; r < 16; r++) acc[r] = 0.f;

  for (int s = 0; s < 4; s++) {
    if (s) __syncthreads();
    {
      float4 w0 = *(const float4*)(wp + s * 64);
      float4 w1 = *(const float4*)(wp + s * 64 + 4);
      float4 w2 = *(const float4*)(wp + s * 64 + 8);
      float4 w3 = *(const float4*)(wp + s * 64 + 12);
      bf16x8 va, vb;
      va[0] = (bf16_t)w0.x; va[1] = (bf16_t)w0.y; va[2] = (bf16_t)w0.z; va[3] = (bf16_t)w0.w;
      va[4] = (bf16_t)w1.x; va[5] = (bf16_t)w1.y; va[6] = (bf16_t)w1.z; va[7] = (bf16_t)w1.w;
      vb[0] = (bf16_t)w2.x; vb[1] = (bf16_t)w2.y; vb[2] = (bf16_t)w2.z; vb[3] = (bf16_t)w2.w;
      vb[4] = (bf16_t)w3.x; vb[5] = (bf16_t)w3.y; vb[6] = (bf16_t)w3.z; vb[7] = (bf16_t)w3.w;
      *(bf16x8*)&WS[lr * 72 + lc] = va;
      *(bf16x8*)&WS[lr * 72 + lc + 8] = vb;
      float4 h0 = *(const float4*)(hp + s * 64);
      float4 h1 = *(const float4*)(hp + s * 64 + 4);
      float4 h2 = *(const float4*)(hp + s * 64 + 8);
      float4 h3 = *(const float4*)(hp + s * 64 + 12);
      bf16x8 vc, vd;
      vc[0] = (bf16_t)h0.x; vc[1] = (bf16_t)h0.y; vc[2] = (bf16_t)h0.z; vc[3] = (bf16_t)h0.w;
      vc[4] = (bf16_t)h1.x; vc[5] = (bf16_t)h1.y; vc[6] = (bf16_t)h1.z; vc[7] = (bf16_t)h1.w;
      vd[0] = (bf16_t)h2.x; vd[1] = (bf16_t)h2.y; vd[2] = (bf16_t)h2.z; vd[3] = (bf16_t)h2.w;
      vd[4] = (bf16_t)h3.x; vd[5] = (bf16_t)h3.y; vd[6] = (bf16_t)h3.z; vd[7] = (bf16_t)h3.w;
      *(bf16x8*)&HS[lr * 72 + lc] = vc;
      *(bf16x8*)&HS[lr * 72 + lc + 8] = vd;
    }
    __syncthreads();
#pragma unroll
    for (int ks = 0; ks < 4; ks++) {
      bf16x8 af = *(const bf16x8*)&WS[(fsub + mrow) * 72 + ks * 16 + half * 8];
      bf16x8 bf = *(const bf16x8*)&HS[(jsub + mrow) * 72 + ks * 16 + half * 8];
      acc = __builtin_amdgcn_mfma_f32_32x32x16_bf16(af, bf, acc, 0, 0, 0);
    }
  }

  // D: col(j)=lane&31, row(f)=(reg&3)+8*(reg>>2)+4*half
  const int jcol = j0 + jsub + mrow;
#pragma unroll
  for (int r = 0; r < 16; r++) {
    int frow = fsub + (r & 3) + 8 * (r >> 2) + 4 * half;
    WhT[(((size_t)(b * 256 + f0 + frow)) << 10) + jcol] = (bf16_t)acc[r];
  }
}

// ---------------- Kernel 2: src[m] = h[m]·u1, dst[m] = h[m]·u2 (fp32 exact) ----------------
// 512 blocks x 256 thr; block = 16 nodes; thread: node n=t>>4, col-group c=t&15 (16 d each).
__global__ __launch_bounds__(256) void k_src(
    const float* __restrict__ h, const float* __restrict__ u,
    float* __restrict__ src, float* __restrict__ dst)
{
  __shared__ float uS[512];
  const int t = threadIdx.x;
  uS[t] = u[t];
  uS[256 + t] = u[256 + t];
  __syncthreads();
  const int n = t >> 4, c = t & 15;
  const int m = blockIdx.x * 16 + n;
  const float* hp = h + (size_t)m * 256 + c * 16;
  float s1 = 0.f, s2 = 0.f;
#pragma unroll
  for (int i = 0; i < 4; i++) {
    float4 v = *(const float4*)(hp + i * 4);
    const float* u1p = &uS[c * 16 + i * 4];
    const float* u2p = &uS[256 + c * 16 + i * 4];
    s1 = fmaf(v.x, u1p[0], s1); s1 = fmaf(v.y, u1p[1], s1);
    s1 = fmaf(v.z, u1p[2], s1); s1 = fmaf(v.w, u1p[3], s1);
    s2 = fmaf(v.x, u2p[0], s2); s2 = fmaf(v.y, u2p[1], s2);
    s2 = fmaf(v.z, u2p[2], s2); s2 = fmaf(v.w, u2p[3], s2);
  }
#pragma unroll
  for (int off = 8; off; off >>= 1) {
    s1 += __shfl_down(s1, off, 16);
    s2 += __shfl_down(s2, off, 16);
  }
  if (c == 0) { src[m] = s1; dst[m] = s2; }
}

// ---------------- Kernel 3: row stats (max, 1/sumexp) + interleaved adjacency bitmask ----------------
// Mask word layout (ballot-native): word (row, wv*4+k) bit s = adj[row][256*wv + 4*s + k].
__global__ __launch_bounds__(256) void k_stats(
    const int* __restrict__ adj, const float* __restrict__ src, const float* __restrict__ dst,
    float* __restrict__ m_ws, float* __restrict__ linv_ws,
    unsigned long long* __restrict__ mask_ws)
{
  const int b  = blockIdx.x & 7;
  const int i0 = (blockIdx.x >> 3) << 3;   // 8 rows per block
  const int t  = threadIdx.x;
  const int wv = t >> 6, lane = t & 63;
  __shared__ float dstS[1024];
  __shared__ float srcS[8];
  __shared__ float partM[8][4], partL[8][4];
  *(float4*)&dstS[t * 4] = *(const float4*)(dst + (b << 10) + t * 4);
  if (t < 8) srcS[t] = src[(b << 10) + i0 + t];
  __syncthreads();

  for (int i = 0; i < 8; i++) {
    float si = srcS[i];
    const size_t row = (size_t)(b << 10) + i0 + i;
    const int4 av = *(const int4*)(adj + (row << 10) + 4 * t);   // j = 4t..4t+3
    float4 dj = *(const float4*)&dstS[4 * t];
    float e4[4];
    {
      float v0 = si + dj.x, v1 = si + dj.y, v2 = si + dj.z, v3 = si + dj.w;
      e4[0] = (av.x > 0) ? fmaxf(v0, ALPHA * v0) : NEG_INF;
      e4[1] = (av.y > 0) ? fmaxf(v1, ALPHA * v1) : NEG_INF;
      e4[2] = (av.z > 0) ? fmaxf(v2, ALPHA * v2) : NEG_INF;
      e4[3] = (av.w > 0) ? fmaxf(v3, ALPHA * v3) : NEG_INF;
    }
    unsigned long long b0 = __ballot(av.x > 0);
    unsigned long long b1 = __ballot(av.y > 0);
    unsigned long long b2 = __ballot(av.z > 0);
    unsigned long long b3 = __ballot(av.w > 0);
    if (lane == 0) {
      unsigned long long* mp = mask_ws + row * 16 + wv * 4;
      mp[0] = b0; mp[1] = b1; mp[2] = b2; mp[3] = b3;
    }
    float mt = fmaxf(fmaxf(e4[0], e4[1]), fmaxf(e4[2], e4[3]));
    float lt = __expf(e4[0] - mt) + __expf(e4[1] - mt) +
               __expf(e4[2] - mt) + __expf(e4[3] - mt);
#pragma unroll
    for (int off = 32; off; off >>= 1) {
      float m2 = __shfl_down(mt, off, 64);
      float l2 = __shfl_down(lt, off, 64);
      float nm = fmaxf(mt, m2);
      lt = lt * __expf(mt - nm) + l2 * __expf(m2 - nm);
      mt = nm;
    }
    if (lane == 0) { partM[i][wv] = mt; partL[i][wv] = lt; }
  }
  __syncthreads();
  if (t < 8) {
    float M = fmaxf(fmaxf(partM[t][0], partM[t][1]), fmaxf(partM[t][2], partM[t][3]));
    float L = partL[t][0] * __expf(partM[t][0] - M) + partL[t][1] * __expf(partM[t][1] - M) +
              partL[t][2] * __expf(partM[t][2] - M) + partL[t][3] * __expf(partM[t][3] - M);
    m_ws[(b << 10) + i0 + t] = M;
    linv_ws[(b << 10) + i0 + t] = 1.0f / L;
  }
}

// ---------------- Kernel 4: P (bf16) + MFMA aggregation ----------------
__global__ __launch_bounds__(256) void k_attn(
    const bf16_t* __restrict__ WhT, const float* __restrict__ src, const float* __restrict__ dst,
    const float* __restrict__ m_ws, const float* __restrict__ linv_ws,
    const unsigned long long* __restrict__ mask_ws, float* __restrict__ out)
{
  const int b  = blockIdx.x & 7;
  const int fh = (blockIdx.x >> 3) & 1;
  const int i0 = (blockIdx.x >> 4) << 5;
  const int t  = threadIdx.x;
  const int w  = t >> 6;
  const int lane = t & 63;
  const int mrow = lane & 31, half = lane >> 5;

  __shared__ float dstS[1024];
  __shared__ float srcS[32], mS[32], lInvS[32];
  __shared__ unsigned long long maskS[32 * 16];
  __shared__ bf16_t P[32 * 264];
  __shared__ bf16_t WhS[128 * 72];

  *(float4*)&dstS[t * 4] = *(const float4*)(dst + (b << 10) + t * 4);
  if (t < 32) {
    srcS[t]  = src[(b << 10) + i0 + t];
    mS[t]    = m_ws[(b << 10) + i0 + t];
    lInvS[t] = linv_ws[(b << 10) + i0 + t];
  }
  {
    const size_t mb = ((size_t)(b << 10) + i0) * 16;
    maskS[t]       = mask_ws[mb + t];
    maskS[t + 256] = mask_ws[mb + t + 256];
  }
  __syncthreads();

  f32x16 acc;
#pragma unroll
  for (int r = 0; r < 16; r++) acc[r] = 0.f;

  const size_t whbase = ((size_t)(b * 256 + fh * 128)) << 10;

  for (int c = 0; c < 4; c++) {
    {
      float dj = dstS[c * 256 + t];
      int mi = c * 4 + (t & 3);    // interleaved mask word
      int sh = t >> 2;             // bit position
#pragma unroll 8
      for (int i = 0; i < 32; i++) {
        unsigned long long w64 = maskS[i * 16 + mi];
        float v = srcS[i] + dj;
        float vl = fmaxf(v, ALPHA * v);
        float e = ((w64 >> sh) & 1ull) ? vl : NEG_INF;
        P[i * 264 + t] = (bf16_t)__expf(e - mS[i]);
      }
    }
    __syncthreads();

    for (int s = 0; s < 4; s++) {
      const size_t gbase = whbase + c * 256 + s * 64;
#pragma unroll
      for (int it = 0; it < 4; it++) {
        int idx = it * 256 + t;
        int f  = idx >> 3;
        int jb = (idx & 7) << 3;
        uint4 v = *(const uint4*)(WhT + gbase + ((size_t)f << 10) + jb);
        *(uint4*)&WhS[f * 72 + jb] = v;
      }
      __syncthreads();
#pragma unroll
      for (int ks = 0; ks < 4; ks++) {
        bf16x8 af = *(const bf16x8*)&P[mrow * 264 + s * 64 + ks * 16 + half * 8];
        bf16x8 bf = *(const bf16x8*)&WhS[(w * 32 + mrow) * 72 + ks * 16 + half * 8];
        acc = __builtin_amdgcn_mfma_f32_32x32x16_bf16(af, bf, acc, 0, 0, 0);
      }
      __syncthreads();
    }
  }

  const int col = fh * 128 + w * 32 + mrow;
#pragma unroll
  for (int r = 0; r < 16; r++) {
    int row = (r & 3) + 8 * (r >> 2) + 4 * half;
    out[((size_t)(b << 10) + i0 + row) * 256 + col] = acc[r] * lInvS[row];
  }
}

// ---------------- Launch ----------------
extern "C" void kernel_launch(void* const* d_in, const int* in_sizes, int n_in,
                              void* d_out, int out_size, void* d_ws, size_t ws_size,
                              hipStream_t stream) {
  const float* h   = (const float*)d_in[0];
  const int*   adj = (const int*)d_in[1];
  const float* W   = (const float*)d_in[2];
  const float* a   = (const float*)d_in[3];
  float* out = (float*)d_out;

  char* wsb = (char*)d_ws;
  bf16_t* WhT = (bf16_t*)wsb;
  float* srcv = (float*)(wsb + (4u << 20));
  float* dstv = srcv + 8192;
  float* m_ws = srcv + 16384;
  float* linv = srcv + 24576;
  unsigned long long* mask_ws = (unsigned long long*)(wsb + (4u << 20) + 131072);
  float* u_ws = (float*)(wsb + (5u << 20) + 131072);

  k_prep <<<1,    256, 0, stream>>>(W, a, u_ws);
  k_gemm1<<<512,  256, 0, stream>>>(h, W, WhT);
  k_src  <<<512,  256, 0, stream>>>(h, u_ws, srcv, dstv);
  k_stats<<<1024, 256, 0, stream>>>(adj, srcv, dstv, m_ws, linv, mask_ws);
  k_attn <<<512,  256, 0, stream>>>(WhT, srcv, dstv, m_ws, linv, mask_ws, out);
}

// Round 4
// 128.541 us; speedup vs baseline: 1.5655x; 1.0180x over previous
//
#include <hip/hip_runtime.h>
#include <hip/hip_bf16.h>
#include <cstdint>

#define ALPHA 0.2f
#define NEG_INF -9000000000000000.0f
// B=8, N=1024, Din=Dout=256, M = 8192
// ws layout:
//   WhT bf16 [8][256][1024]   @ 0            (4 MiB)  B^T layout for MFMA B-frags
//   src  f32 [8192]           @ 4 MiB
//   dst  f32 [8192]           @ 4 MiB + 32 KiB
//   m    f32 [8192]           @ 4 MiB + 64 KiB
//   linv f32 [8192]           @ 4 MiB + 96 KiB
//   mask u64 [8192][16]       @ 4 MiB + 128 KiB  (1 MiB)
//   u1/u2 f32 [512]           @ 5 MiB + 128 KiB  (2 KiB)

typedef __bf16 bf16_t;
typedef __bf16 bf16x8 __attribute__((ext_vector_type(8)));
typedef float f32x16 __attribute__((ext_vector_type(16)));

// ---------------- Kernel 0: u1 = W^T a1, u2 = W^T a2 (one block) ----------------
__global__ __launch_bounds__(256) void k_prep(
    const float* __restrict__ W, const float* __restrict__ a, float* __restrict__ u)
{
  const int d = threadIdx.x;
  float s1a = 0.f, s1b = 0.f, s2a = 0.f, s2b = 0.f;
#pragma unroll 4
  for (int f = 0; f < 256; f += 2) {
    float w0 = W[f * 256 + d];
    float w1 = W[(f + 1) * 256 + d];
    s1a = fmaf(w0, a[f], s1a);       s1b = fmaf(w1, a[f + 1], s1b);
    s2a = fmaf(w0, a[256 + f], s2a); s2b = fmaf(w1, a[256 + f + 1], s2b);
  }
  u[d] = s1a + s1b;
  u[256 + d] = s2a + s2b;
}

// ---------------- Kernel 1: WhT[b][f][j] = bf16( sum_d W[f][d] h[bj][d] ) via MFMA ----------------
__global__ __launch_bounds__(256) void k_gemm1(
    const float* __restrict__ h, const float* __restrict__ W, bf16_t* __restrict__ WhT)
{
  __shared__ bf16_t WS[64 * 72];   // [f_local][d_chunk], stride 72
  __shared__ bf16_t HS[64 * 72];   // [j_local][d_chunk]
  const int bx = blockIdx.x;
  const int b  = bx & 7;
  const int jt = (bx >> 3) & 15;
  const int ft = bx >> 7;
  const int j0 = jt * 64, f0 = ft * 64;
  const int t = threadIdx.x;
  const int w = t >> 6, lane = t & 63;
  const int mrow = lane & 31, half = lane >> 5;
  const int fsub = (w & 1) * 32, jsub = (w >> 1) * 32;

  const int lr = t >> 2;          // 0..63 (row)
  const int lc = (t & 3) * 16;    // 0,16,32,48 (col group)
  const float* wp = W + ((size_t)(f0 + lr)) * 256 + lc;
  const float* hp = h + ((size_t)(b * 1024 + j0 + lr)) * 256 + lc;

  f32x16 acc;
#pragma unroll
  for (int r = 0; r < 16; r++) acc[r] = 0.f;

  for (int s = 0; s < 4; s++) {
    if (s) __syncthreads();
    {
      float4 w0 = *(const float4*)(wp + s * 64);
      float4 w1 = *(const float4*)(wp + s * 64 + 4);
      float4 w2 = *(const float4*)(wp + s * 64 + 8);
      float4 w3 = *(const float4*)(wp + s * 64 + 12);
      bf16x8 va, vb;
      va[0] = (bf16_t)w0.x; va[1] = (bf16_t)w0.y; va[2] = (bf16_t)w0.z; va[3] = (bf16_t)w0.w;
      va[4] = (bf16_t)w1.x; va[5] = (bf16_t)w1.y; va[6] = (bf16_t)w1.z; va[7] = (bf16_t)w1.w;
      vb[0] = (bf16_t)w2.x; vb[1] = (bf16_t)w2.y; vb[2] = (bf16_t)w2.z; vb[3] = (bf16_t)w2.w;
      vb[4] = (bf16_t)w3.x; vb[5] = (bf16_t)w3.y; vb[6] = (bf16_t)w3.z; vb[7] = (bf16_t)w3.w;
      *(bf16x8*)&WS[lr * 72 + lc] = va;
      *(bf16x8*)&WS[lr * 72 + lc + 8] = vb;
      float4 h0 = *(const float4*)(hp + s * 64);
      float4 h1 = *(const float4*)(hp + s * 64 + 4);
      float4 h2 = *(const float4*)(hp + s * 64 + 8);
      float4 h3 = *(const float4*)(hp + s * 64 + 12);
      bf16x8 vc, vd;
      vc[0] = (bf16_t)h0.x; vc[1] = (bf16_t)h0.y; vc[2] = (bf16_t)h0.z; vc[3] = (bf16_t)h0.w;
      vc[4] = (bf16_t)h1.x; vc[5] = (bf16_t)h1.y; vc[6] = (bf16_t)h1.z; vc[7] = (bf16_t)h1.w;
      vd[0] = (bf16_t)h2.x; vd[1] = (bf16_t)h2.y; vd[2] = (bf16_t)h2.z; vd[3] = (bf16_t)h2.w;
      vd[4] = (bf16_t)h3.x; vd[5] = (bf16_t)h3.y; vd[6] = (bf16_t)h3.z; vd[7] = (bf16_t)h3.w;
      *(bf16x8*)&HS[lr * 72 + lc] = vc;
      *(bf16x8*)&HS[lr * 72 + lc + 8] = vd;
    }
    __syncthreads();
#pragma unroll
    for (int ks = 0; ks < 4; ks++) {
      bf16x8 af = *(const bf16x8*)&WS[(fsub + mrow) * 72 + ks * 16 + half * 8];
      bf16x8 bf = *(const bf16x8*)&HS[(jsub + mrow) * 72 + ks * 16 + half * 8];
      acc = __builtin_amdgcn_mfma_f32_32x32x16_bf16(af, bf, acc, 0, 0, 0);
    }
  }

  // D: col(j)=lane&31, row(f)=(reg&3)+8*(reg>>2)+4*half
  const int jcol = j0 + jsub + mrow;
#pragma unroll
  for (int r = 0; r < 16; r++) {
    int frow = fsub + (r & 3) + 8 * (r >> 2) + 4 * half;
    WhT[(((size_t)(b * 256 + f0 + frow)) << 10) + jcol] = (bf16_t)acc[r];
  }
}

// ---------------- Kernel 2: src[m] = h[m]·u1, dst[m] = h[m]·u2 (fp32 exact) ----------------
__global__ __launch_bounds__(256) void k_src(
    const float* __restrict__ h, const float* __restrict__ u,
    float* __restrict__ src, float* __restrict__ dst)
{
  __shared__ float uS[512];
  const int t = threadIdx.x;
  uS[t] = u[t];
  uS[256 + t] = u[256 + t];
  __syncthreads();
  const int n = t >> 4, c = t & 15;
  const int m = blockIdx.x * 16 + n;
  const float* hp = h + (size_t)m * 256 + c * 16;
  float s1 = 0.f, s2 = 0.f;
#pragma unroll
  for (int i = 0; i < 4; i++) {
    float4 v = *(const float4*)(hp + i * 4);
    const float* u1p = &uS[c * 16 + i * 4];
    const float* u2p = &uS[256 + c * 16 + i * 4];
    s1 = fmaf(v.x, u1p[0], s1); s1 = fmaf(v.y, u1p[1], s1);
    s1 = fmaf(v.z, u1p[2], s1); s1 = fmaf(v.w, u1p[3], s1);
    s2 = fmaf(v.x, u2p[0], s2); s2 = fmaf(v.y, u2p[1], s2);
    s2 = fmaf(v.z, u2p[2], s2); s2 = fmaf(v.w, u2p[3], s2);
  }
#pragma unroll
  for (int off = 8; off; off >>= 1) {
    s1 += __shfl_down(s1, off, 16);
    s2 += __shfl_down(s2, off, 16);
  }
  if (c == 0) { src[m] = s1; dst[m] = s2; }
}

// ---------------- Kernel 3: row stats (max, 1/sumexp) + interleaved adjacency bitmask ----------------
// Mask word layout (ballot-native): word (row, wv*4+k) bit s = adj[row][256*wv + 4*s + k].
__global__ __launch_bounds__(256) void k_stats(
    const int* __restrict__ adj, const float* __restrict__ src, const float* __restrict__ dst,
    float* __restrict__ m_ws, float* __restrict__ linv_ws,
    unsigned long long* __restrict__ mask_ws)
{
  const int b  = blockIdx.x & 7;
  const int i0 = (blockIdx.x >> 3) << 3;   // 8 rows per block
  const int t  = threadIdx.x;
  const int wv = t >> 6, lane = t & 63;
  __shared__ float dstS[1024];
  __shared__ float srcS[8];
  __shared__ float partM[8][4], partL[8][4];
  *(float4*)&dstS[t * 4] = *(const float4*)(dst + (b << 10) + t * 4);
  if (t < 8) srcS[t] = src[(b << 10) + i0 + t];
  __syncthreads();

  for (int i = 0; i < 8; i++) {
    float si = srcS[i];
    const size_t row = (size_t)(b << 10) + i0 + i;
    const int4 av = *(const int4*)(adj + (row << 10) + 4 * t);   // j = 4t..4t+3
    float4 dj = *(const float4*)&dstS[4 * t];
    float e4[4];
    {
      float v0 = si + dj.x, v1 = si + dj.y, v2 = si + dj.z, v3 = si + dj.w;
      e4[0] = (av.x > 0) ? fmaxf(v0, ALPHA * v0) : NEG_INF;
      e4[1] = (av.y > 0) ? fmaxf(v1, ALPHA * v1) : NEG_INF;
      e4[2] = (av.z > 0) ? fmaxf(v2, ALPHA * v2) : NEG_INF;
      e4[3] = (av.w > 0) ? fmaxf(v3, ALPHA * v3) : NEG_INF;
    }
    unsigned long long b0 = __ballot(av.x > 0);
    unsigned long long b1 = __ballot(av.y > 0);
    unsigned long long b2 = __ballot(av.z > 0);
    unsigned long long b3 = __ballot(av.w > 0);
    if (lane == 0) {
      unsigned long long* mp = mask_ws + row * 16 + wv * 4;
      mp[0] = b0; mp[1] = b1; mp[2] = b2; mp[3] = b3;
    }
    float mt = fmaxf(fmaxf(e4[0], e4[1]), fmaxf(e4[2], e4[3]));
    float lt = __expf(e4[0] - mt) + __expf(e4[1] - mt) +
               __expf(e4[2] - mt) + __expf(e4[3] - mt);
#pragma unroll
    for (int off = 32; off; off >>= 1) {
      float m2 = __shfl_down(mt, off, 64);
      float l2 = __shfl_down(lt, off, 64);
      float nm = fmaxf(mt, m2);
      lt = lt * __expf(mt - nm) + l2 * __expf(m2 - nm);
      mt = nm;
    }
    if (lane == 0) { partM[i][wv] = mt; partL[i][wv] = lt; }
  }
  __syncthreads();
  if (t < 8) {
    float M = fmaxf(fmaxf(partM[t][0], partM[t][1]), fmaxf(partM[t][2], partM[t][3]));
    float L = partL[t][0] * __expf(partM[t][0] - M) + partL[t][1] * __expf(partM[t][1] - M) +
              partL[t][2] * __expf(partM[t][2] - M) + partL[t][3] * __expf(partM[t][3] - M);
    m_ws[(b << 10) + i0 + t] = M;
    linv_ws[(b << 10) + i0 + t] = 1.0f / L;
  }
}

// ---------------- Kernel 4: P (bf16, LDS double-buffer) + MFMA with B-frags direct from global ----------------
// grid 512 = b(8) x fhalf(2) x itile(32). 4 waves; wave w owns f-tile fh*128 + w*32.
// B-frag = 8 contiguous j of WhT row f: loaded per-lane straight from global (L2-resident).
// Barriers: 1 per j-chunk (P dbuf) + 1 after header = 5 total.
__global__ __launch_bounds__(256) void k_attn(
    const bf16_t* __restrict__ WhT, const float* __restrict__ src, const float* __restrict__ dst,
    const float* __restrict__ m_ws, const float* __restrict__ linv_ws,
    const unsigned long long* __restrict__ mask_ws, float* __restrict__ out)
{
  const int b  = blockIdx.x & 7;
  const int fh = (blockIdx.x >> 3) & 1;
  const int i0 = (blockIdx.x >> 4) << 5;
  const int t  = threadIdx.x;
  const int w  = t >> 6;
  const int lane = t & 63;
  const int mrow = lane & 31, half = lane >> 5;

  __shared__ float dstS[1024];
  __shared__ float srcS[32], mS[32], lInvS[32];
  __shared__ unsigned long long maskS[32 * 16];
  __shared__ bf16_t P[2][32 * 264];   // double buffer

  *(float4*)&dstS[t * 4] = *(const float4*)(dst + (b << 10) + t * 4);
  if (t < 32) {
    srcS[t]  = src[(b << 10) + i0 + t];
    mS[t]    = m_ws[(b << 10) + i0 + t];
    lInvS[t] = linv_ws[(b << 10) + i0 + t];
  }
  {
    const size_t mb = ((size_t)(b << 10) + i0) * 16;
    maskS[t]       = mask_ws[mb + t];
    maskS[t + 256] = mask_ws[mb + t + 256];
  }
  __syncthreads();

  f32x16 acc;
#pragma unroll
  for (int r = 0; r < 16; r++) acc[r] = 0.f;

  // lane's B-frag row: f = fh*128 + w*32 + mrow
  const bf16_t* bp = WhT + (((size_t)(b * 256 + fh * 128 + w * 32 + mrow)) << 10);

  for (int c = 0; c < 4; c++) {
    bf16_t* Pc = &P[c & 1][0];
    {
      float dj = dstS[c * 256 + t];
      int mi = c * 4 + (t & 3);    // interleaved mask word
      int sh = t >> 2;             // bit position
#pragma unroll 8
      for (int i = 0; i < 32; i++) {
        unsigned long long w64 = maskS[i * 16 + mi];
        float v = srcS[i] + dj;
        float vl = fmaxf(v, ALPHA * v);
        float e = ((w64 >> sh) & 1ull) ? vl : NEG_INF;
        Pc[i * 264 + t] = (bf16_t)__expf(e - mS[i]);
      }
    }
    __syncthreads();   // P[c&1] ready; also guarantees prior reads of this buffer done (2-chunk gap)

    const bf16_t* bpc = bp + c * 256 + half * 8;
    const bf16_t* prow = Pc + mrow * 264 + half * 8;
#pragma unroll
    for (int idx = 0; idx < 16; idx++) {
      bf16x8 bf = *(const bf16x8*)(bpc + idx * 16);
      bf16x8 af = *(const bf16x8*)(prow + idx * 16);
      acc = __builtin_amdgcn_mfma_f32_32x32x16_bf16(af, bf, acc, 0, 0, 0);
    }
  }

  const int col = fh * 128 + w * 32 + mrow;
#pragma unroll
  for (int r = 0; r < 16; r++) {
    int row = (r & 3) + 8 * (r >> 2) + 4 * half;
    out[((size_t)(b << 10) + i0 + row) * 256 + col] = acc[r] * lInvS[row];
  }
}

// ---------------- Launch ----------------
extern "C" void kernel_launch(void* const* d_in, const int* in_sizes, int n_in,
                              void* d_out, int out_size, void* d_ws, size_t ws_size,
                              hipStream_t stream) {
  const float* h   = (const float*)d_in[0];
  const int*   adj = (const int*)d_in[1];
  const float* W   = (const float*)d_in[2];
  const float* a   = (const float*)d_in[3];
  float* out = (float*)d_out;

  char* wsb = (char*)d_ws;
  bf16_t* WhT = (bf16_t*)wsb;
  float* srcv = (float*)(wsb + (4u << 20));
  float* dstv = srcv + 8192;
  float* m_ws = srcv + 16384;
  float* linv = srcv + 24576;
  unsigned long long* mask_ws = (unsigned long long*)(wsb + (4u << 20) + 131072);
  float* u_ws = (float*)(wsb + (5u << 20) + 131072);

  k_prep <<<1,    256, 0, stream>>>(W, a, u_ws);
  k_gemm1<<<512,  256, 0, stream>>>(h, W, WhT);
  k_src  <<<512,  256, 0, stream>>>(h, u_ws, srcv, dstv);
  k_stats<<<1024, 256, 0, stream>>>(adj, srcv, dstv, m_ws, linv, mask_ws);
  k_attn <<<512,  256, 0, stream>>>(WhT, srcv, dstv, m_ws, linv, mask_ws, out);
}